// Round 1
// baseline (9232.517 us; speedup 1.0000x reference)
//
#include <hip/hip_runtime.h>
#include <cstdint>
#include <cstddef>

#define S_  512
#define H_  1024
#define H3  3072
#define OUT_OFF 4194304  // B*S*O

typedef __attribute__((ext_vector_type(8))) short  short8;
typedef __attribute__((ext_vector_type(4))) float  f32x4;
typedef __attribute__((ext_vector_type(4))) unsigned short us4;
typedef __attribute__((ext_vector_type(4))) unsigned int   u32x4;
typedef unsigned long long u64;

#define MFMA __builtin_amdgcn_mfma_f32_16x16x32_bf16

// ---- workspace layout (bytes) ----
static const size_t XP_OFF    = 0;            // bf16 [512][3072][32]
static const size_t H2_OFF    = 100663296;    // bf16 [16384][1024]
static const size_t XBF_OFF   = 134217728;    // bf16 [16384][256]
static const size_t WX0B_OFF  = 142606336;
static const size_t WZR0_OFF  = 144179200;
static const size_t WG0_OFF   = 148373504;
static const size_t WZR1_OFF  = 150470656;
static const size_t WGX1_OFF  = 158859264;
static const size_t WG1_OFF   = 160956416;
static const size_t WZR2_OFF  = 163053568;
static const size_t WGX2_OFF  = 171442176;
static const size_t WG2_OFF   = 173539328;
static const size_t WOUTB_OFF = 175636480;
static const size_t ZBU_OFF   = 176160768;    // u64 [3][1024][16] fp32-pair z
static const size_t GXB_OFF   = 176553984;    // u64 [3][1024][16] fp32-pair gx
static const size_t HROW_OFF  = 176947200;    // f32 [3][1024][32] block-local h
static const size_t FLAG_OFF  = 177340416;    // 4096: gbar flags[256] | flagA[256] | flagB[256]
static const size_t HH_OFF    = 177344512;    // hist h: u64 [515][3][256kc][32b]
static const size_t RHH_OFF   = 278597632;    // hist rh: u64 [514][3][256][32]
static const size_t WS_HIST   = 379654144;
static const size_t WS_BASE   = 177737728;    // HH used as single-slot h+rh

__device__ inline unsigned short f2bf(float f){
  unsigned u = __builtin_bit_cast(unsigned, f);
  unsigned r = u + 0x7fffu + ((u >> 16) & 1u);
  return (unsigned short)(r >> 16);
}
__device__ inline float bf2f(unsigned short s){
  unsigned u = ((unsigned)s) << 16;
  return __builtin_bit_cast(float, u);
}
__device__ inline unsigned ld_sys(const unsigned* p){
  return __hip_atomic_load(p, __ATOMIC_RELAXED, __HIP_MEMORY_SCOPE_SYSTEM);
}
__device__ inline void st_sys(unsigned* p, unsigned v){
  __hip_atomic_store(p, v, __ATOMIC_RELAXED, __HIP_MEMORY_SCOPE_SYSTEM);
}
__device__ inline u64 ld64(const u64* p){
  return __hip_atomic_load(p, __ATOMIC_RELAXED, __HIP_MEMORY_SCOPE_SYSTEM);
}
__device__ inline void st64(u64* p, u64 v){
  __hip_atomic_store(p, v, __ATOMIC_RELAXED, __HIP_MEMORY_SCOPE_SYSTEM);
}
template<bool HIST>
__device__ inline u64 LD(const u64* p){
  if constexpr (HIST) return *p; else return ld64(p);
}
__device__ inline short8 mk8u(u64 a, u64 b){
  u32x4 u; u.x = (unsigned)a; u.y = (unsigned)(a >> 32); u.z = (unsigned)b; u.w = (unsigned)(b >> 32);
  return __builtin_bit_cast(short8, u);
}
__device__ inline u64 pk4(float a, float b, float c, float d){
  return (u64)f2bf(a) | ((u64)f2bf(b) << 16) | ((u64)f2bf(c) << 32) | ((u64)f2bf(d) << 48);
}
__device__ inline u64 pk2f(float a, float b){
  return (u64)__builtin_bit_cast(unsigned, a) | ((u64)__builtin_bit_cast(unsigned, b) << 32);
}
__device__ inline float lo32f(u64 u){ return __builtin_bit_cast(float, (unsigned)u); }
__device__ inline float hi32f(u64 u){ return __builtin_bit_cast(float, (unsigned)(u >> 32)); }

// ---------------- prep kernels ----------------
__global__ void k_conv(const float* __restrict__ src, unsigned short* __restrict__ dst, int n){
  int i = blockIdx.x*256 + threadIdx.x;
  if (i < n) dst[i] = f2bf(src[i]);
}
__global__ void k_packzr(const float* __restrict__ Wh, const float* __restrict__ Wx,
                         unsigned short* __restrict__ dst){
  size_t i = (size_t)blockIdx.x*256 + threadIdx.x;
  int k = (int)(i & 2047);
  int n = (int)(i >> 11);
  float v = (k < 1024) ? Wh[(size_t)n*1024 + k] : Wx[(size_t)n*1024 + (k - 1024)];
  dst[i] = f2bf(v);
}
__global__ void k_convx(const float* __restrict__ x, unsigned short* __restrict__ xbf){
  int row = blockIdx.x;
  int s = row >> 5, b = row & 31;
  int i = threadIdx.x;
  xbf[(size_t)row*256 + i] = f2bf(x[((size_t)b*S_ + s)*256 + i]);
}

// ---------------- bf16 MFMA GEMM (proven) ----------------
__global__ __launch_bounds__(256) void k_gemm(const unsigned short* __restrict__ A,
                                              const unsigned short* __restrict__ Bw,
                                              const float* __restrict__ bias,
                                              void* __restrict__ Cout,
                                              int Kd, int mode, int Nd){
  __shared__ __align__(16) unsigned short lA[128*40];
  __shared__ __align__(16) unsigned short lB[128*40];
  int bm = blockIdx.y * 128, bn = blockIdx.x * 128;
  int tid = threadIdx.x;
  int w = tid >> 6, lane = tid & 63, q = lane >> 4, cc = lane & 15;
  int wm = (w >> 1) * 64, wn = (w & 1) * 64;
  f32x4 acc[4][4] = {};
  for (int k0 = 0; k0 < Kd; k0 += 32){
    #pragma unroll
    for (int i = 0; i < 2; i++){
      int idx = tid + i*256;
      int r = idx >> 2, ch = idx & 3;
      int m = bm + r;
      int arow = (mode == 0) ? m : ((m & 511)*32 + (m >> 9));
      *(u32x4*)(lA + r*40 + ch*8) = *(const u32x4*)(A + (size_t)arow*Kd + k0 + ch*8);
      *(u32x4*)(lB + r*40 + ch*8) = *(const u32x4*)(Bw + (size_t)(bn + r)*Kd + k0 + ch*8);
    }
    __syncthreads();
    short8 af[4], bfv[4];
    #pragma unroll
    for (int i = 0; i < 4; i++) af[i]  = *(const short8*)(lA + (wm + i*16 + cc)*40 + q*8);
    #pragma unroll
    for (int i = 0; i < 4; i++) bfv[i] = *(const short8*)(lB + (wn + i*16 + cc)*40 + q*8);
    #pragma unroll
    for (int i = 0; i < 4; i++)
      #pragma unroll
      for (int j = 0; j < 4; j++)
        acc[i][j] = MFMA(af[i], bfv[j], acc[i][j], 0, 0, 0);
    __syncthreads();
  }
  if (mode == 0){
    unsigned short* xp = (unsigned short*)Cout;
    #pragma unroll
    for (int i = 0; i < 4; i++){
      #pragma unroll
      for (int j = 0; j < 4; j++){
        int m = bm + wm + i*16 + q*4;
        int n = bn + wn + j*16 + cc;
        float bv = bias[n];
        int s = m >> 5, b0 = m & 31;
        us4 pk;
        #pragma unroll
        for (int reg = 0; reg < 4; reg++) pk[reg] = f2bf(acc[i][j][reg] + bv);
        *(us4*)(xp + ((size_t)s*H3 + n)*32 + b0) = pk;
      }
    }
  } else {
    float* C = (float*)Cout;
    #pragma unroll
    for (int i = 0; i < 4; i++){
      #pragma unroll
      for (int j = 0; j < 4; j++){
        int m = bm + wm + i*16 + q*4;
        int n = bn + wn + j*16 + cc;
        float bv = bias[n];
        #pragma unroll
        for (int reg = 0; reg < 4; reg++)
          C[(size_t)(m + reg)*Nd + n] = acc[i][j][reg] + bv;
      }
    }
  }
}

// ---------------- barriers / dataflow flags ----------------
__device__ inline void gbar(unsigned* flags, unsigned ep){
  __syncthreads();
  if (threadIdx.x == 0) st_sys(flags + blockIdx.x, ep);
  if (threadIdx.x < 64){
    for (;;){
      unsigned v0 = ld_sys(flags + threadIdx.x);
      unsigned v1 = ld_sys(flags + 64 + threadIdx.x);
      unsigned v2 = ld_sys(flags + 128 + threadIdx.x);
      unsigned v3 = ld_sys(flags + 192 + threadIdx.x);
      if (__all((v0 >= ep) && (v1 >= ep) && (v2 >= ep) && (v3 >= ep))) break;
      __builtin_amdgcn_s_sleep(1);
    }
  }
  __syncthreads();
}

// wait until flags[lo..hi) >= ep (hi-lo multiple of 64). One wave polls,
// all waves released by the trailing block barrier.
__device__ inline void waitflags(const unsigned* f, int lo, int hi, unsigned ep){
  if (threadIdx.x < 64){
    const unsigned* p = f + lo + threadIdx.x;
    int n = hi - lo;
    for (;;){
      bool ok = true;
      #pragma unroll 1
      for (int k = 0; k < n; k += 64) ok &= (ld_sys(p + k) >= ep);
      if (__all(ok)) break;
      __builtin_amdgcn_s_sleep(1);
    }
  }
  __syncthreads();
}

// matvec, k-major A layout [kc][b] (u64 chunks of 4 bf16).
// p0 = base + (kc0 + q*2)*32 + c ; per iter +256 (8 chunks). acc1 = b+16.
template<int NITER, bool HIST>
__device__ inline void matvec(const u64* p0, const unsigned short* wp,
                              f32x4& acc0, f32x4& acc1){
  u64 buf[2][4][4];
  #pragma unroll
  for (int ii = 0; ii < 4; ii++){
    const u64* p = p0 + ii*256;
    buf[0][ii][0] = LD<HIST>(p);      buf[0][ii][1] = LD<HIST>(p + 32);
    buf[0][ii][2] = LD<HIST>(p + 16); buf[0][ii][3] = LD<HIST>(p + 48);
  }
  constexpr int NCH = NITER / 4;
  #pragma unroll
  for (int ch = 0; ch < NCH; ch++){
    const int cur = ch & 1, nxt = cur ^ 1;
    if (ch + 1 < NCH){
      #pragma unroll
      for (int ii = 0; ii < 4; ii++){
        const u64* p = p0 + ((ch+1)*4 + ii)*256;
        buf[nxt][ii][0] = LD<HIST>(p);      buf[nxt][ii][1] = LD<HIST>(p + 32);
        buf[nxt][ii][2] = LD<HIST>(p + 16); buf[nxt][ii][3] = LD<HIST>(p + 48);
      }
    }
    #pragma unroll
    for (int ii = 0; ii < 4; ii++){
      short8 bw = *(const short8*)(wp + (ch*4 + ii)*32);
      acc0 = MFMA(mk8u(buf[cur][ii][0], buf[cur][ii][1]), bw, acc0, 0, 0, 0);
      acc1 = MFMA(mk8u(buf[cur][ii][2], buf[cur][ii][3]), bw, acc1, 0, 0, 0);
    }
  }
}

// ---------------- fused 3-layer pipelined persistent recurrence ----------------
// MODE 0: single-slot, global barriers.  MODE 2: per-T slots, point-to-point
// dataflow flags (no grid-wide barrier).
template<int MODE>
__global__ __launch_bounds__(256, 1) void k_fused(char* __restrict__ ws,
                                                  const float* __restrict__ h0,
                                                  const float* __restrict__ bh,
                                                  float* __restrict__ outp,
                                                  u64* __restrict__ hh,
                                                  u64* __restrict__ rhh){
  constexpr bool HIST = (MODE >= 1);
  constexpr bool DF   = (MODE == 2);

  __shared__ __align__(16) unsigned short wlds[65920];
  __shared__ __align__(16) float red[2][3][64][10];
  __shared__ float rtA[16*33];
  __shared__ float rtB[16*33];

  const int tid = threadIdx.x;
  const int w = tid >> 6, lane = tid & 63, q = (lane >> 4) & 3, c = lane & 15;
  const int i = blockIdx.x;

  const int lz   = 1 + (i >> 7);
  const int g2   = (i >> 6) & 1;
  const int n2   = (i & 63) << 4;
  const bool isl0 = (i < 128);
  const int g1   = (i >> 6) & 1;
  const int lgx  = 1 + ((i >> 6) & 1);
  const int n1   = (i & 63) << 4;
  const bool hasB = (i < 192);
  const int lb   = i >> 6;
  const int nb   = (i & 63) << 4;

  // phase-B consumers wait on phase-A producers in these block ranges
  const int alo = (lb == 2) ? 128 : 0;
  const int ahi = (lb == 0) ? 128 : (lb == 1 ? 192 : 256);

  const unsigned short* xp = (const unsigned short*)(ws + XP_OFF);
  u64* h2u   = (u64*)(ws + H2_OFF);
  u64* zbu   = (u64*)(ws + ZBU_OFF);
  u64* gxb   = (u64*)(ws + GXB_OFF);
  float* hrow = (float*)(ws + HROW_OFF);
  unsigned* flags = (unsigned*)(ws + FLAG_OFF);
  unsigned* flagA = flags + 256;   // per-block phase-A completion epoch
  unsigned* flagB = flags + 512;   // per-block phase-B completion epoch

  // ---- stage weights into LDS ----
  {
    const unsigned short* src2 = (const unsigned short*)(ws + (lz == 1 ? WZR1_OFF : WZR2_OFF))
                                 + (size_t)(g2*1024 + n2)*2048;
    for (int idx = tid; idx < 4096; idx += 256){
      int kc = idx & 255, row = idx >> 8;
      u32x4 v = *(const u32x4*)(src2 + (size_t)row*2048 + kc*8);
      *(u32x4*)(wlds + row*2056 + kc*8) = v;
    }
    const unsigned short* src1 = isl0
      ? (const unsigned short*)(ws + WZR0_OFF) + (size_t)(g1*1024 + n1)*1024
      : (const unsigned short*)(ws + (lgx == 1 ? WGX1_OFF : WGX2_OFF)) + (size_t)n1*1024;
    for (int idx = tid; idx < 2048; idx += 256){
      int kc = idx & 127, row = idx >> 7;
      u32x4 v = *(const u32x4*)(src1 + (size_t)row*1024 + kc*8);
      *(u32x4*)(wlds + 32896 + row*1032 + kc*8) = v;
    }
    if (hasB){
      const unsigned short* srcb = (const unsigned short*)(ws + (lb == 0 ? WG0_OFF : (lb == 1 ? WG1_OFF : WG2_OFF)))
                                   + (size_t)nb*1024;
      for (int idx = tid; idx < 2048; idx += 256){
        int kc = idx & 127, row = idx >> 7;
        u32x4 v = *(const u32x4*)(srcb + (size_t)row*1024 + kc*8);
        *(u32x4*)(wlds + 49408 + row*1032 + kc*8) = v;
      }
    }
  }
  const float biasT2 = bh[(size_t)(lz-1)*H3 + g2*1024 + n2 + c];
  const float biasGX = isl0 ? 0.f : bh[(size_t)(lgx-1)*H3 + 2048 + n1 + c];

  // ---- init h state ----
  if (hasB){
    for (int idx = tid; idx < 512; idx += 256){
      int n = idx >> 5, b = idx & 31;
      float v = h0[((size_t)b*3 + lb)*H_ + nb + n];
      hrow[((size_t)lb*1024 + nb + n)*32 + b] = v;
      rtA[n*33 + b] = v;
    }
  }
  __syncthreads();
  if (hasB && tid < 128){
    int b = tid & 31, p2 = tid >> 5;
    u64 pkv = pk4(rtA[(4*p2+0)*33+b], rtA[(4*p2+1)*33+b], rtA[(4*p2+2)*33+b], rtA[(4*p2+3)*33+b]);
    st64(hh + (size_t)(HIST ? lb : 0)*24576 + (size_t)lb*8192 + (size_t)((nb >> 2) + p2)*32 + b, pkv);
  }
  unsigned ep = 1;
  if constexpr (DF){
    __syncthreads();
    if (tid == 0 && hasB) st_sys(flagB + i, (unsigned)(lb + 1));  // slot lb ready
  } else {
    gbar(flags, ep); ep++;
  }

  for (int T = 0; T < 514; T++){
    const int t2 = T - lz;
    const bool actT2 = (unsigned)t2 < 512u;
    const int t1 = isl0 ? T : (T - lgx);
    const bool actT1 = (unsigned)t1 < 512u;
    const int tb = T - lb;
    const bool actB = hasB && ((unsigned)tb < 512u);

    const u64* hslotR = hh + (size_t)(HIST ? T : 0)*24576;
    u64*       rslot  = rhh + (size_t)(HIST ? T : 0)*24576;

    if constexpr (DF){
      // wait for hh slot T (layers this block reads) + WAR cover for zbu/gxb
      int lo = 256, hi = 0;
      if (actT2){ int a = 64*(lz-1), b = 64*(lz+1); if (a < lo) lo = a; if (b > hi) hi = b; }
      if (actT1){
        int a = isl0 ? 0 : 64*(lgx-1);
        int b = isl0 ? 64 : 64*(lgx+1);
        if (a < lo) lo = a; if (b > hi) hi = b;
      }
      if (hi > lo) waitflags(flagB, lo, hi, (unsigned)(T + 1));
    }

    // ================= phase A =================
    f32x4 z20 = {0,0,0,0}, z21 = {0,0,0,0};
    f32x4 z10 = {0,0,0,0}, z11 = {0,0,0,0};
    if (actT2){
      const u64* p0 = hslotR + (size_t)((w < 2) ? lz : (lz-1))*8192 + (size_t)((w & 1)*128 + q*2)*32 + c;
      const unsigned short* wp = wlds + c*2056 + w*512 + q*8;
      matvec<16, HIST>(p0, wp, z20, z21);
    }
    if (actT1){
      const u64* p0 = hslotR + (size_t)(isl0 ? 0 : (lgx-1))*8192 + (size_t)(w*64 + q*2)*32 + c;
      const unsigned short* wp = wlds + 32896 + c*1032 + w*256 + q*8;
      matvec<8, HIST>(p0, wp, z10, z11);
    }
    if (actT2 && w > 0){
      float* p = &red[0][w-1][lane][0];
      #pragma unroll
      for (int r = 0; r < 4; r++){ p[r] = z20[r]; p[4+r] = z21[r]; }
    }
    if (actT1 && w != 1){
      float* p = &red[1][(w == 0) ? 0 : (w-1)][lane][0];
      #pragma unroll
      for (int r = 0; r < 4; r++){ p[r] = z10[r]; p[4+r] = z11[r]; }
    }
    __syncthreads();
    if (w == 0 && actT2){
      #pragma unroll
      for (int s = 0; s < 3; s++){
        const float* p = &red[0][s][lane][0];
        #pragma unroll
        for (int r = 0; r < 4; r++){ z20[r] += p[r]; z21[r] += p[4+r]; }
      }
      const int kidx = (n2 + c) >> 2, sh = (c & 3)*16;
      const u64* hlz = hslotR + (size_t)lz*8192;
      #pragma unroll
      for (int mt = 0; mt < 2; mt++){
        float f[4];
        #pragma unroll
        for (int r = 0; r < 4; r++){
          float pre = (mt ? z21[r] : z20[r]) + biasT2;
          f[r] = 1.0f / (1.0f + __expf(-pre));
        }
        if (g2 == 0){
          u64* zp = zbu + ((size_t)lz*1024 + n2 + c)*16 + mt*8 + q*2;
          st64(zp, pk2f(f[0], f[1])); st64(zp + 1, pk2f(f[2], f[3]));
        } else {
          #pragma unroll
          for (int r = 0; r < 4; r++){
            int b = mt*16 + q*4 + r;
            u64 hw = LD<HIST>(hlz + (size_t)kidx*32 + b);
            rtA[c*33 + b] = f[r] * bf2f((unsigned short)(hw >> sh));
          }
        }
      }
    }
    if (w == 1 && actT1){
      #pragma unroll
      for (int s = 0; s < 3; s++){
        const float* p = &red[1][s][lane][0];
        #pragma unroll
        for (int r = 0; r < 4; r++){ z10[r] += p[r]; z11[r] += p[4+r]; }
      }
      if (isl0){
        const int kidx = (n1 + c) >> 2, sh = (c & 3)*16;
        const unsigned short* xr = xp + ((size_t)t1*H3 + g1*1024 + n1 + c)*32;
        #pragma unroll
        for (int mt = 0; mt < 2; mt++){
          us4 xv = *(const us4*)(xr + mt*16 + q*4);
          float f[4];
          #pragma unroll
          for (int r = 0; r < 4; r++){
            float pre = (mt ? z11[r] : z10[r]) + bf2f(xv[r]);
            f[r] = 1.0f / (1.0f + __expf(-pre));
          }
          if (g1 == 0){
            u64* zp = zbu + ((size_t)n1 + c)*16 + mt*8 + q*2;
            st64(zp, pk2f(f[0], f[1])); st64(zp + 1, pk2f(f[2], f[3]));
          } else {
            #pragma unroll
            for (int r = 0; r < 4; r++){
              int b = mt*16 + q*4 + r;
              u64 hw = LD<HIST>(hslotR + (size_t)kidx*32 + b);
              rtB[c*33 + b] = f[r] * bf2f((unsigned short)(hw >> sh));
            }
          }
        }
      } else {
        #pragma unroll
        for (int mt = 0; mt < 2; mt++){
          float f[4];
          #pragma unroll
          for (int r = 0; r < 4; r++) f[r] = (mt ? z11[r] : z10[r]) + biasGX;
          u64* gp = gxb + ((size_t)lgx*1024 + n1 + c)*16 + mt*8 + q*2;
          st64(gp, pk2f(f[0], f[1])); st64(gp + 1, pk2f(f[2], f[3]));
        }
      }
    }
    __syncthreads();
    if (g2 == 1 && actT2 && tid < 128){
      int b = tid & 31, p2 = tid >> 5;
      st64(rslot + (size_t)lz*8192 + (size_t)((n2 >> 2) + p2)*32 + b,
           pk4(rtA[(4*p2+0)*33+b], rtA[(4*p2+1)*33+b], rtA[(4*p2+2)*33+b], rtA[(4*p2+3)*33+b]));
    }
    if (isl0 && g1 == 1 && actT1 && tid >= 128){
      int tt = tid - 128; int b = tt & 31, p2 = tt >> 5;
      st64(rslot + (size_t)((n1 >> 2) + p2)*32 + b,
           pk4(rtB[(4*p2+0)*33+b], rtB[(4*p2+1)*33+b], rtB[(4*p2+2)*33+b], rtB[(4*p2+3)*33+b]));
    }
    if constexpr (DF){
      __syncthreads();
      if (tid == 0 && (actT2 || actT1)) st_sys(flagA + i, (unsigned)(T + 1));
      if (actB) waitflags(flagA, alo, ahi, (unsigned)(T + 1));
    } else {
      gbar(flags, ep); ep++;
    }

    // ================= phase B =================
    f32x4 gb0 = {0,0,0,0}, gb1 = {0,0,0,0};
    if (actB){
      const u64* p0 = (const u64*)rslot + (size_t)lb*8192 + (size_t)(w*64 + q*2)*32 + c;
      const unsigned short* wp = wlds + 49408 + c*1032 + w*256 + q*8;
      matvec<8, HIST>(p0, wp, gb0, gb1);
      if (w > 0){
        float* p = &red[0][w-1][lane][0];
        #pragma unroll
        for (int r = 0; r < 4; r++){ p[r] = gb0[r]; p[4+r] = gb1[r]; }
      }
    }
    __syncthreads();
    if (actB && w == 0){
      #pragma unroll
      for (int s = 0; s < 3; s++){
        const float* p = &red[0][s][lane][0];
        #pragma unroll
        for (int r = 0; r < 4; r++){ gb0[r] += p[r]; gb1[r] += p[4+r]; }
      }
      #pragma unroll
      for (int mt = 0; mt < 2; mt++){
        float gadd[4];
        if (lb == 0){
          us4 xv = *(const us4*)(xp + ((size_t)tb*H3 + 2048 + nb + c)*32 + mt*16 + q*4);
          #pragma unroll
          for (int r = 0; r < 4; r++) gadd[r] = bf2f(xv[r]);
        } else {
          const u64* gp = gxb + ((size_t)lb*1024 + nb + c)*16 + mt*8 + q*2;
          u64 u01 = ld64(gp), u23 = ld64(gp + 1);
          gadd[0] = lo32f(u01); gadd[1] = hi32f(u01); gadd[2] = lo32f(u23); gadd[3] = hi32f(u23);
        }
        const u64* zp = zbu + ((size_t)lb*1024 + nb + c)*16 + mt*8 + q*2;
        u64 z01 = ld64(zp), z23 = ld64(zp + 1);
        float zf[4] = { lo32f(z01), hi32f(z01), lo32f(z23), hi32f(z23) };
        float* hp = hrow + ((size_t)lb*1024 + nb + c)*32 + mt*16 + q*4;
        f32x4 h4 = *(const f32x4*)hp;
        f32x4 hn4;
        #pragma unroll
        for (int r = 0; r < 4; r++){
          float gpre = (mt ? gb1[r] : gb0[r]) + gadd[r];
          float gv = tanhf(gpre);
          float hnv = zf[r]*h4[r] + (1.0f - zf[r])*gv;
          hn4[r] = hnv;
          rtA[c*33 + mt*16 + q*4 + r] = hnv;
          if (tb == 511) outp[OUT_OFF + ((size_t)(mt*16 + q*4 + r)*3 + lb)*H_ + nb + c] = hnv;
        }
        *(f32x4*)hp = hn4;
      }
    }
    __syncthreads();
    if (actB && tid < 128){
      int b = tid & 31, p2 = tid >> 5;
      u64 pkv = pk4(rtA[(4*p2+0)*33+b], rtA[(4*p2+1)*33+b], rtA[(4*p2+2)*33+b], rtA[(4*p2+3)*33+b]);
      st64(hh + (size_t)(HIST ? (T + 1) : 0)*24576 + (size_t)lb*8192 + (size_t)((nb >> 2) + p2)*32 + b, pkv);
      if (lb == 2) *(u64*)(h2u + ((size_t)tb*32 + b)*256 + (nb >> 2) + p2) = pkv;
    }
    if constexpr (DF){
      __syncthreads();
      if (tid == 0 && actB) st_sys(flagB + i, (unsigned)(T + 2));  // slot T+1 ready
    } else {
      gbar(flags, ep); ep++;
    }
  }
  (void)ep;
}

extern "C" void kernel_launch(void* const* d_in, const int* in_sizes, int n_in,
                              void* d_out, int out_size, void* d_ws, size_t ws_size,
                              hipStream_t stream){
  (void)in_sizes; (void)n_in; (void)out_size;
  if (ws_size < WS_BASE) return;
  const bool hist = (ws_size >= WS_HIST);

  const float* x    = (const float*)d_in[0];
  const float* h0   = (const float*)d_in[1];
  const float* Wx0  = (const float*)d_in[2];
  const float* Wh0  = (const float*)d_in[3];
  const float* bh0  = (const float*)d_in[4];
  const float* Wx   = (const float*)d_in[5];
  const float* Wh   = (const float*)d_in[6];
  const float* bh   = (const float*)d_in[7];
  const float* Wout = (const float*)d_in[8];
  const float* bout = (const float*)d_in[9];
  float* out = (float*)d_out;

  char* ws = (char*)d_ws;
  unsigned short* xp    = (unsigned short*)(ws + XP_OFF);
  unsigned short* h2    = (unsigned short*)(ws + H2_OFF);
  unsigned short* xbf   = (unsigned short*)(ws + XBF_OFF);
  unsigned short* wx0b  = (unsigned short*)(ws + WX0B_OFF);
  unsigned short* wzr0  = (unsigned short*)(ws + WZR0_OFF);
  unsigned short* wg0   = (unsigned short*)(ws + WG0_OFF);
  unsigned short* wzr1  = (unsigned short*)(ws + WZR1_OFF);
  unsigned short* wgx1  = (unsigned short*)(ws + WGX1_OFF);
  unsigned short* wg1   = (unsigned short*)(ws + WG1_OFF);
  unsigned short* wzr2  = (unsigned short*)(ws + WZR2_OFF);
  unsigned short* wgx2  = (unsigned short*)(ws + WGX2_OFF);
  unsigned short* wg2   = (unsigned short*)(ws + WG2_OFF);
  unsigned short* woutb = (unsigned short*)(ws + WOUTB_OFF);
  u64* hh  = (u64*)(ws + HH_OFF);
  u64* rhh = hist ? (u64*)(ws + RHH_OFF) : (hh + 24576);

  hipMemsetAsync(ws + FLAG_OFF, 0, 4096, stream);

  k_conv<<<3072, 256, 0, stream>>>(Wx0, wx0b, 786432);
  k_conv<<<8192, 256, 0, stream>>>(Wh0, wzr0, 2097152);
  k_conv<<<4096, 256, 0, stream>>>(Wh0 + 2097152, wg0, 1048576);
  k_packzr<<<16384, 256, 0, stream>>>(Wh, Wx, wzr1);
  k_conv<<<4096, 256, 0, stream>>>(Wx + 2097152, wgx1, 1048576);
  k_conv<<<4096, 256, 0, stream>>>(Wh + 2097152, wg1, 1048576);
  k_packzr<<<16384, 256, 0, stream>>>(Wh + 3145728, Wx + 3145728, wzr2);
  k_conv<<<4096, 256, 0, stream>>>(Wx + 5242880, wgx2, 1048576);
  k_conv<<<4096, 256, 0, stream>>>(Wh + 5242880, wg2, 1048576);
  k_conv<<<1024, 256, 0, stream>>>(Wout, woutb, 262144);
  k_convx<<<16384, 256, 0, stream>>>(x, xbf);

  {
    dim3 g(24, 128);
    k_gemm<<<g, 256, 0, stream>>>(xbf, wx0b, bh0, (void*)xp, 256, 0, H3);
  }
  if (hist) k_fused<2><<<256, 256, 0, stream>>>(ws, h0, bh, out, hh, rhh);
  else      k_fused<0><<<256, 256, 0, stream>>>(ws, h0, bh, out, hh, rhh);
  {
    dim3 g(2, 128);
    k_gemm<<<g, 256, 0, stream>>>(h2, woutb, bout, (void*)out, 1024, 1, 256);
  }
}

// Round 2
// 7414.332 us; speedup vs baseline: 1.2452x; 1.2452x over previous
//
#include <hip/hip_runtime.h>
#include <cstdint>
#include <cstddef>

#define S_  512
#define H_  1024
#define H3  3072
#define OUT_OFF 4194304  // B*S*O

typedef __attribute__((ext_vector_type(8))) short  short8;
typedef __attribute__((ext_vector_type(4))) float  f32x4;
typedef __attribute__((ext_vector_type(4))) unsigned short us4;
typedef __attribute__((ext_vector_type(4))) unsigned int   u32x4;
typedef unsigned long long u64;

#define MFMA __builtin_amdgcn_mfma_f32_16x16x32_bf16

// ---- workspace layout (bytes) ----
static const size_t XP_OFF    = 0;            // bf16 [512][3072][32]
static const size_t H2_OFF    = 100663296;    // bf16 [16384][1024]
static const size_t XBF_OFF   = 134217728;    // bf16 [16384][256]
static const size_t WX0B_OFF  = 142606336;
static const size_t WZR0_OFF  = 144179200;
static const size_t WG0_OFF   = 148373504;
static const size_t WZR1_OFF  = 150470656;
static const size_t WGX1_OFF  = 158859264;
static const size_t WG1_OFF   = 160956416;
static const size_t WZR2_OFF  = 163053568;
static const size_t WGX2_OFF  = 171442176;
static const size_t WG2_OFF   = 173539328;
static const size_t WOUTB_OFF = 175636480;
static const size_t ZBU_OFF   = 176160768;    // u64 [3][1024][16] fp32-pair z
static const size_t GXB_OFF   = 176553984;    // u64 [3][1024][16] fp32-pair gx
static const size_t HROW_OFF  = 176947200;    // f32 [3][1024][32] block-local h
static const size_t FLAG_OFF  = 177340416;    // 4096: gbar flags[256] | flagA[256] | flagB[256]
static const size_t HH_OFF    = 177344512;    // hist h: u64 [515][3][256kc][32b]
static const size_t RHH_OFF   = 278597632;    // hist rh: u64 [514][3][256][32]
static const size_t WS_HIST   = 379654144;
static const size_t WS_BASE   = 177737728;    // HH used as single-slot h+rh

__device__ inline unsigned short f2bf(float f){
  unsigned u = __builtin_bit_cast(unsigned, f);
  unsigned r = u + 0x7fffu + ((u >> 16) & 1u);
  return (unsigned short)(r >> 16);
}
__device__ inline float bf2f(unsigned short s){
  unsigned u = ((unsigned)s) << 16;
  return __builtin_bit_cast(float, u);
}
__device__ inline unsigned ld_sys(const unsigned* p){
  return __hip_atomic_load(p, __ATOMIC_RELAXED, __HIP_MEMORY_SCOPE_SYSTEM);
}
__device__ inline void st_sys(unsigned* p, unsigned v){
  __hip_atomic_store(p, v, __ATOMIC_RELAXED, __HIP_MEMORY_SCOPE_SYSTEM);
}
__device__ inline u64 ld64(const u64* p){
  return __hip_atomic_load(p, __ATOMIC_RELAXED, __HIP_MEMORY_SCOPE_SYSTEM);
}
__device__ inline void st64(u64* p, u64 v){
  __hip_atomic_store(p, v, __ATOMIC_RELAXED, __HIP_MEMORY_SCOPE_SYSTEM);
}
template<bool HIST>
__device__ inline u64 LD(const u64* p){
  if constexpr (HIST) return *p; else return ld64(p);
}
__device__ inline short8 mk8u(u64 a, u64 b){
  u32x4 u; u.x = (unsigned)a; u.y = (unsigned)(a >> 32); u.z = (unsigned)b; u.w = (unsigned)(b >> 32);
  return __builtin_bit_cast(short8, u);
}
__device__ inline u64 pk4(float a, float b, float c, float d){
  return (u64)f2bf(a) | ((u64)f2bf(b) << 16) | ((u64)f2bf(c) << 32) | ((u64)f2bf(d) << 48);
}
__device__ inline u64 pk2f(float a, float b){
  return (u64)__builtin_bit_cast(unsigned, a) | ((u64)__builtin_bit_cast(unsigned, b) << 32);
}
__device__ inline float lo32f(u64 u){ return __builtin_bit_cast(float, (unsigned)u); }
__device__ inline float hi32f(u64 u){ return __builtin_bit_cast(float, (unsigned)(u >> 32)); }

// ---------------- prep kernels ----------------
__global__ void k_conv(const float* __restrict__ src, unsigned short* __restrict__ dst, int n){
  int i = blockIdx.x*256 + threadIdx.x;
  if (i < n) dst[i] = f2bf(src[i]);
}
__global__ void k_packzr(const float* __restrict__ Wh, const float* __restrict__ Wx,
                         unsigned short* __restrict__ dst){
  size_t i = (size_t)blockIdx.x*256 + threadIdx.x;
  int k = (int)(i & 2047);
  int n = (int)(i >> 11);
  float v = (k < 1024) ? Wh[(size_t)n*1024 + k] : Wx[(size_t)n*1024 + (k - 1024)];
  dst[i] = f2bf(v);
}
__global__ void k_convx(const float* __restrict__ x, unsigned short* __restrict__ xbf){
  int row = blockIdx.x;
  int s = row >> 5, b = row & 31;
  int i = threadIdx.x;
  xbf[(size_t)row*256 + i] = f2bf(x[((size_t)b*S_ + s)*256 + i]);
}

// ---------------- bf16 MFMA GEMM (proven) ----------------
__global__ __launch_bounds__(256) void k_gemm(const unsigned short* __restrict__ A,
                                              const unsigned short* __restrict__ Bw,
                                              const float* __restrict__ bias,
                                              void* __restrict__ Cout,
                                              int Kd, int mode, int Nd){
  __shared__ __align__(16) unsigned short lA[128*40];
  __shared__ __align__(16) unsigned short lB[128*40];
  int bm = blockIdx.y * 128, bn = blockIdx.x * 128;
  int tid = threadIdx.x;
  int w = tid >> 6, lane = tid & 63, q = lane >> 4, cc = lane & 15;
  int wm = (w >> 1) * 64, wn = (w & 1) * 64;
  f32x4 acc[4][4] = {};
  for (int k0 = 0; k0 < Kd; k0 += 32){
    #pragma unroll
    for (int i = 0; i < 2; i++){
      int idx = tid + i*256;
      int r = idx >> 2, ch = idx & 3;
      int m = bm + r;
      int arow = (mode == 0) ? m : ((m & 511)*32 + (m >> 9));
      *(u32x4*)(lA + r*40 + ch*8) = *(const u32x4*)(A + (size_t)arow*Kd + k0 + ch*8);
      *(u32x4*)(lB + r*40 + ch*8) = *(const u32x4*)(Bw + (size_t)(bn + r)*Kd + k0 + ch*8);
    }
    __syncthreads();
    short8 af[4], bfv[4];
    #pragma unroll
    for (int i = 0; i < 4; i++) af[i]  = *(const short8*)(lA + (wm + i*16 + cc)*40 + q*8);
    #pragma unroll
    for (int i = 0; i < 4; i++) bfv[i] = *(const short8*)(lB + (wn + i*16 + cc)*40 + q*8);
    #pragma unroll
    for (int i = 0; i < 4; i++)
      #pragma unroll
      for (int j = 0; j < 4; j++)
        acc[i][j] = MFMA(af[i], bfv[j], acc[i][j], 0, 0, 0);
    __syncthreads();
  }
  if (mode == 0){
    unsigned short* xp = (unsigned short*)Cout;
    #pragma unroll
    for (int i = 0; i < 4; i++){
      #pragma unroll
      for (int j = 0; j < 4; j++){
        int m = bm + wm + i*16 + q*4;
        int n = bn + wn + j*16 + cc;
        float bv = bias[n];
        int s = m >> 5, b0 = m & 31;
        us4 pk;
        #pragma unroll
        for (int reg = 0; reg < 4; reg++) pk[reg] = f2bf(acc[i][j][reg] + bv);
        *(us4*)(xp + ((size_t)s*H3 + n)*32 + b0) = pk;
      }
    }
  } else {
    float* C = (float*)Cout;
    #pragma unroll
    for (int i = 0; i < 4; i++){
      #pragma unroll
      for (int j = 0; j < 4; j++){
        int m = bm + wm + i*16 + q*4;
        int n = bn + wn + j*16 + cc;
        float bv = bias[n];
        #pragma unroll
        for (int reg = 0; reg < 4; reg++)
          C[(size_t)(m + reg)*Nd + n] = acc[i][j][reg] + bv;
      }
    }
  }
}

// ---------------- barriers / dataflow flags ----------------
__device__ inline void gbar(unsigned* flags, unsigned ep){
  __syncthreads();
  if (threadIdx.x == 0) st_sys(flags + blockIdx.x, ep);
  if (threadIdx.x < 64){
    for (;;){
      unsigned v0 = ld_sys(flags + threadIdx.x);
      unsigned v1 = ld_sys(flags + 64 + threadIdx.x);
      unsigned v2 = ld_sys(flags + 128 + threadIdx.x);
      unsigned v3 = ld_sys(flags + 192 + threadIdx.x);
      if (__all((v0 >= ep) && (v1 >= ep) && (v2 >= ep) && (v3 >= ep))) break;
      __builtin_amdgcn_s_sleep(1);
    }
  }
  __syncthreads();
}

// wait until flags[lo..hi) >= ep (hi-lo multiple of 64). One wave polls with
// INDEPENDENT loads (one L3 round-trip per poll), all waves released by the
// trailing block barrier.
__device__ inline void waitflags(const unsigned* f, int lo, int hi, unsigned ep){
  if (threadIdx.x < 64){
    const unsigned* p = f + lo + threadIdx.x;
    const int n = hi - lo;
    const bool h1 = (n > 64), h2 = (n > 128);
    for (;;){
      unsigned v0 = ld_sys(p);
      unsigned v1 = h1 ? ld_sys(p + 64)  : 0xffffffffu;
      unsigned v2 = h2 ? ld_sys(p + 128) : 0xffffffffu;
      if (__all((v0 >= ep) && (v1 >= ep) && (v2 >= ep))) break;
      __builtin_amdgcn_s_sleep(1);
    }
  }
  __syncthreads();
}

// matvec, k-major A layout [kc][b] (u64 chunks of 4 bf16).
// p0 = base + (kc0 + q*2)*32 + c ; per iter +256 (8 chunks). acc1 = b+16.
template<int NITER, bool HIST>
__device__ inline void matvec(const u64* p0, const unsigned short* wp,
                              f32x4& acc0, f32x4& acc1){
  u64 buf[2][4][4];
  #pragma unroll
  for (int ii = 0; ii < 4; ii++){
    const u64* p = p0 + ii*256;
    buf[0][ii][0] = LD<HIST>(p);      buf[0][ii][1] = LD<HIST>(p + 32);
    buf[0][ii][2] = LD<HIST>(p + 16); buf[0][ii][3] = LD<HIST>(p + 48);
  }
  constexpr int NCH = NITER / 4;
  #pragma unroll
  for (int ch = 0; ch < NCH; ch++){
    const int cur = ch & 1, nxt = cur ^ 1;
    if (ch + 1 < NCH){
      #pragma unroll
      for (int ii = 0; ii < 4; ii++){
        const u64* p = p0 + ((ch+1)*4 + ii)*256;
        buf[nxt][ii][0] = LD<HIST>(p);      buf[nxt][ii][1] = LD<HIST>(p + 32);
        buf[nxt][ii][2] = LD<HIST>(p + 16); buf[nxt][ii][3] = LD<HIST>(p + 48);
      }
    }
    #pragma unroll
    for (int ii = 0; ii < 4; ii++){
      short8 bw = *(const short8*)(wp + (ch*4 + ii)*32);
      acc0 = MFMA(mk8u(buf[cur][ii][0], buf[cur][ii][1]), bw, acc0, 0, 0, 0);
      acc1 = MFMA(mk8u(buf[cur][ii][2], buf[cur][ii][3]), bw, acc1, 0, 0, 0);
    }
  }
}

// ---------------- fused 3-layer pipelined persistent recurrence ----------------
// MODE 0: single-slot, global barriers.  MODE 2: per-T slots, point-to-point
// dataflow flags (no grid-wide barrier).
template<int MODE>
__global__ __launch_bounds__(256, 1) void k_fused(char* __restrict__ ws,
                                                  const float* __restrict__ h0,
                                                  const float* __restrict__ bh,
                                                  float* __restrict__ outp,
                                                  u64* __restrict__ hh,
                                                  u64* __restrict__ rhh){
  constexpr bool HIST = (MODE >= 1);
  constexpr bool DF   = (MODE == 2);

  __shared__ __align__(16) unsigned short wlds[65920];
  __shared__ __align__(16) float red[2][3][64][10];
  __shared__ float rtA[16*33];
  __shared__ float rtB[16*33];

  const int tid = threadIdx.x;
  const int w = tid >> 6, lane = tid & 63, q = (lane >> 4) & 3, c = lane & 15;
  const int i = blockIdx.x;

  const int lz   = 1 + (i >> 7);
  const int g2   = (i >> 6) & 1;
  const int n2   = (i & 63) << 4;
  const bool isl0 = (i < 128);
  const int g1   = (i >> 6) & 1;
  const int lgx  = 1 + ((i >> 6) & 1);
  const int n1   = (i & 63) << 4;
  const bool hasB = (i < 192);
  const int lb   = i >> 6;
  const int nb   = (i & 63) << 4;

  // phase-B consumers wait on phase-A producers in these block ranges
  const int alo = (lb == 2) ? 128 : 0;
  const int ahi = (lb == 0) ? 128 : (lb == 1 ? 192 : 256);

  const unsigned short* xp = (const unsigned short*)(ws + XP_OFF);
  u64* h2u   = (u64*)(ws + H2_OFF);
  u64* zbu   = (u64*)(ws + ZBU_OFF);
  u64* gxb   = (u64*)(ws + GXB_OFF);
  float* hrow = (float*)(ws + HROW_OFF);
  unsigned* flags = (unsigned*)(ws + FLAG_OFF);
  unsigned* flagA = flags + 256;   // per-block phase-A completion epoch
  unsigned* flagB = flags + 512;   // per-block phase-B completion epoch

  // ---- stage weights into LDS ----
  {
    const unsigned short* src2 = (const unsigned short*)(ws + (lz == 1 ? WZR1_OFF : WZR2_OFF))
                                 + (size_t)(g2*1024 + n2)*2048;
    for (int idx = tid; idx < 4096; idx += 256){
      int kc = idx & 255, row = idx >> 8;
      u32x4 v = *(const u32x4*)(src2 + (size_t)row*2048 + kc*8);
      *(u32x4*)(wlds + row*2056 + kc*8) = v;
    }
    const unsigned short* src1 = isl0
      ? (const unsigned short*)(ws + WZR0_OFF) + (size_t)(g1*1024 + n1)*1024
      : (const unsigned short*)(ws + (lgx == 1 ? WGX1_OFF : WGX2_OFF)) + (size_t)n1*1024;
    for (int idx = tid; idx < 2048; idx += 256){
      int kc = idx & 127, row = idx >> 7;
      u32x4 v = *(const u32x4*)(src1 + (size_t)row*1024 + kc*8);
      *(u32x4*)(wlds + 32896 + row*1032 + kc*8) = v;
    }
    if (hasB){
      const unsigned short* srcb = (const unsigned short*)(ws + (lb == 0 ? WG0_OFF : (lb == 1 ? WG1_OFF : WG2_OFF)))
                                   + (size_t)nb*1024;
      for (int idx = tid; idx < 2048; idx += 256){
        int kc = idx & 127, row = idx >> 7;
        u32x4 v = *(const u32x4*)(srcb + (size_t)row*1024 + kc*8);
        *(u32x4*)(wlds + 49408 + row*1032 + kc*8) = v;
      }
    }
  }
  const float biasT2 = bh[(size_t)(lz-1)*H3 + g2*1024 + n2 + c];
  const float biasGX = isl0 ? 0.f : bh[(size_t)(lgx-1)*H3 + 2048 + n1 + c];

  // ---- init h state ----
  if (hasB){
    for (int idx = tid; idx < 512; idx += 256){
      int n = idx >> 5, b = idx & 31;
      float v = h0[((size_t)b*3 + lb)*H_ + nb + n];
      hrow[((size_t)lb*1024 + nb + n)*32 + b] = v;
      rtA[n*33 + b] = v;
    }
  }
  __syncthreads();
  if (hasB && tid < 128){
    int b = tid & 31, p2 = tid >> 5;
    u64 pkv = pk4(rtA[(4*p2+0)*33+b], rtA[(4*p2+1)*33+b], rtA[(4*p2+2)*33+b], rtA[(4*p2+3)*33+b]);
    st64(hh + (size_t)(HIST ? lb : 0)*24576 + (size_t)lb*8192 + (size_t)((nb >> 2) + p2)*32 + b, pkv);
  }
  unsigned ep = 1;
  if constexpr (DF){
    __syncthreads();
    if (tid == 0 && hasB) st_sys(flagB + i, (unsigned)(lb + 1));  // slot lb ready
  } else {
    gbar(flags, ep); ep++;
  }

  for (int T = 0; T < 514; T++){
    const int t2 = T - lz;
    const bool actT2 = (unsigned)t2 < 512u;
    const int t1 = isl0 ? T : (T - lgx);
    const bool actT1 = (unsigned)t1 < 512u;
    const int tb = T - lb;
    const bool actB = hasB && ((unsigned)tb < 512u);

    const u64* hslotR = hh + (size_t)(HIST ? T : 0)*24576;
    u64*       rslot  = rhh + (size_t)(HIST ? T : 0)*24576;

    if constexpr (DF){
      // wait for hh slot T (layers this block reads) + WAR cover for zbu/gxb
      int lo = 256, hi = 0;
      if (actT2){ int a = 64*(lz-1), b = 64*(lz+1); if (a < lo) lo = a; if (b > hi) hi = b; }
      if (actT1){
        int a = isl0 ? 0 : 64*(lgx-1);
        int b = isl0 ? 64 : 64*(lgx+1);
        if (a < lo) lo = a; if (b > hi) hi = b;
      }
      if (hi > lo) waitflags(flagB, lo, hi, (unsigned)(T + 1));
    }

    // ---- prefetch phase-A epilogue operands (hide L3 latency under matvec) ----
    u64 hpreA[8]; us4 xpreA[2]; u64 hpreL0[8];
    if (actT2 && w == 0 && g2 == 1){
      const u64* hb = hslotR + (size_t)lz*8192 + (size_t)((n2 + c) >> 2)*32 + q*4;
      #pragma unroll
      for (int mt = 0; mt < 2; mt++)
        #pragma unroll
        for (int r = 0; r < 4; r++) hpreA[mt*4+r] = LD<HIST>(hb + mt*16 + r);
    }
    if (actT1 && w == 1 && isl0){
      const unsigned short* xr = xp + ((size_t)t1*H3 + g1*1024 + n1 + c)*32 + q*4;
      xpreA[0] = *(const us4*)(xr);
      xpreA[1] = *(const us4*)(xr + 16);
      if (g1 == 1){
        const u64* hb = hslotR + (size_t)((n1 + c) >> 2)*32 + q*4;
        #pragma unroll
        for (int mt = 0; mt < 2; mt++)
          #pragma unroll
          for (int r = 0; r < 4; r++) hpreL0[mt*4+r] = LD<HIST>(hb + mt*16 + r);
      }
    }

    // ================= phase A =================
    f32x4 z20 = {0,0,0,0}, z21 = {0,0,0,0};
    f32x4 z10 = {0,0,0,0}, z11 = {0,0,0,0};
    if (actT2){
      const u64* p0 = hslotR + (size_t)((w < 2) ? lz : (lz-1))*8192 + (size_t)((w & 1)*128 + q*2)*32 + c;
      const unsigned short* wp = wlds + c*2056 + w*512 + q*8;
      matvec<16, HIST>(p0, wp, z20, z21);
    }
    if (actT1){
      const u64* p0 = hslotR + (size_t)(isl0 ? 0 : (lgx-1))*8192 + (size_t)(w*64 + q*2)*32 + c;
      const unsigned short* wp = wlds + 32896 + c*1032 + w*256 + q*8;
      matvec<8, HIST>(p0, wp, z10, z11);
    }
    if (actT2 && w > 0){
      float* p = &red[0][w-1][lane][0];
      #pragma unroll
      for (int r = 0; r < 4; r++){ p[r] = z20[r]; p[4+r] = z21[r]; }
    }
    if (actT1 && w != 1){
      float* p = &red[1][(w == 0) ? 0 : (w-1)][lane][0];
      #pragma unroll
      for (int r = 0; r < 4; r++){ p[r] = z10[r]; p[4+r] = z11[r]; }
    }
    __syncthreads();
    if (w == 0 && actT2){
      #pragma unroll
      for (int s = 0; s < 3; s++){
        const float* p = &red[0][s][lane][0];
        #pragma unroll
        for (int r = 0; r < 4; r++){ z20[r] += p[r]; z21[r] += p[4+r]; }
      }
      const int sh = (c & 3)*16;
      #pragma unroll
      for (int mt = 0; mt < 2; mt++){
        float f[4];
        #pragma unroll
        for (int r = 0; r < 4; r++){
          float pre = (mt ? z21[r] : z20[r]) + biasT2;
          f[r] = 1.0f / (1.0f + __expf(-pre));
        }
        if (g2 == 0){
          u64* zp = zbu + ((size_t)lz*1024 + n2 + c)*16 + mt*8 + q*2;
          st64(zp, pk2f(f[0], f[1])); st64(zp + 1, pk2f(f[2], f[3]));
        } else {
          #pragma unroll
          for (int r = 0; r < 4; r++){
            int b = mt*16 + q*4 + r;
            rtA[c*33 + b] = f[r] * bf2f((unsigned short)(hpreA[mt*4+r] >> sh));
          }
        }
      }
    }
    if (w == 1 && actT1){
      #pragma unroll
      for (int s = 0; s < 3; s++){
        const float* p = &red[1][s][lane][0];
        #pragma unroll
        for (int r = 0; r < 4; r++){ z10[r] += p[r]; z11[r] += p[4+r]; }
      }
      if (isl0){
        const int sh = (c & 3)*16;
        #pragma unroll
        for (int mt = 0; mt < 2; mt++){
          us4 xv = xpreA[mt];
          float f[4];
          #pragma unroll
          for (int r = 0; r < 4; r++){
            float pre = (mt ? z11[r] : z10[r]) + bf2f(xv[r]);
            f[r] = 1.0f / (1.0f + __expf(-pre));
          }
          if (g1 == 0){
            u64* zp = zbu + ((size_t)n1 + c)*16 + mt*8 + q*2;
            st64(zp, pk2f(f[0], f[1])); st64(zp + 1, pk2f(f[2], f[3]));
          } else {
            #pragma unroll
            for (int r = 0; r < 4; r++){
              int b = mt*16 + q*4 + r;
              rtB[c*33 + b] = f[r] * bf2f((unsigned short)(hpreL0[mt*4+r] >> sh));
            }
          }
        }
      } else {
        #pragma unroll
        for (int mt = 0; mt < 2; mt++){
          float f[4];
          #pragma unroll
          for (int r = 0; r < 4; r++) f[r] = (mt ? z11[r] : z10[r]) + biasGX;
          u64* gp = gxb + ((size_t)lgx*1024 + n1 + c)*16 + mt*8 + q*2;
          st64(gp, pk2f(f[0], f[1])); st64(gp + 1, pk2f(f[2], f[3]));
        }
      }
    }
    __syncthreads();
    if (g2 == 1 && actT2 && tid < 128){
      int b = tid & 31, p2 = tid >> 5;
      st64(rslot + (size_t)lz*8192 + (size_t)((n2 >> 2) + p2)*32 + b,
           pk4(rtA[(4*p2+0)*33+b], rtA[(4*p2+1)*33+b], rtA[(4*p2+2)*33+b], rtA[(4*p2+3)*33+b]));
    }
    if (isl0 && g1 == 1 && actT1 && tid >= 128){
      int tt = tid - 128; int b = tt & 31, p2 = tt >> 5;
      st64(rslot + (size_t)((n1 >> 2) + p2)*32 + b,
           pk4(rtB[(4*p2+0)*33+b], rtB[(4*p2+1)*33+b], rtB[(4*p2+2)*33+b], rtB[(4*p2+3)*33+b]));
    }
    if constexpr (DF){
      __syncthreads();
      if (tid == 0 && (actT2 || actT1)) st_sys(flagA + i, (unsigned)(T + 1));
      if (actB) waitflags(flagA, alo, ahi, (unsigned)(T + 1));
    } else {
      gbar(flags, ep); ep++;
    }

    // ---- prefetch phase-B epilogue operands (hide L3 latency under matvec) ----
    u64 zpreB[4], gpreB[4]; us4 xpreB[2]; f32x4 hpre4[2];
    if (actB && w == 0){
      const u64* zp = zbu + ((size_t)lb*1024 + nb + c)*16 + q*2;
      zpreB[0] = ld64(zp);     zpreB[1] = ld64(zp + 1);
      zpreB[2] = ld64(zp + 8); zpreB[3] = ld64(zp + 9);
      if (lb == 0){
        const unsigned short* xr = xp + ((size_t)tb*H3 + 2048 + nb + c)*32 + q*4;
        xpreB[0] = *(const us4*)(xr);
        xpreB[1] = *(const us4*)(xr + 16);
      } else {
        const u64* gp = gxb + ((size_t)lb*1024 + nb + c)*16 + q*2;
        gpreB[0] = ld64(gp);     gpreB[1] = ld64(gp + 1);
        gpreB[2] = ld64(gp + 8); gpreB[3] = ld64(gp + 9);
      }
      const float* hp0 = hrow + ((size_t)lb*1024 + nb + c)*32 + q*4;
      hpre4[0] = *(const f32x4*)(hp0);
      hpre4[1] = *(const f32x4*)(hp0 + 16);
    }

    // ================= phase B =================
    f32x4 gb0 = {0,0,0,0}, gb1 = {0,0,0,0};
    if (actB){
      const u64* p0 = (const u64*)rslot + (size_t)lb*8192 + (size_t)(w*64 + q*2)*32 + c;
      const unsigned short* wp = wlds + 49408 + c*1032 + w*256 + q*8;
      matvec<8, HIST>(p0, wp, gb0, gb1);
      if (w > 0){
        float* p = &red[0][w-1][lane][0];
        #pragma unroll
        for (int r = 0; r < 4; r++){ p[r] = gb0[r]; p[4+r] = gb1[r]; }
      }
    }
    __syncthreads();
    if (actB && w == 0){
      #pragma unroll
      for (int s = 0; s < 3; s++){
        const float* p = &red[0][s][lane][0];
        #pragma unroll
        for (int r = 0; r < 4; r++){ gb0[r] += p[r]; gb1[r] += p[4+r]; }
      }
      #pragma unroll
      for (int mt = 0; mt < 2; mt++){
        float gadd[4];
        if (lb == 0){
          us4 xv = xpreB[mt];
          #pragma unroll
          for (int r = 0; r < 4; r++) gadd[r] = bf2f(xv[r]);
        } else {
          gadd[0] = lo32f(gpreB[mt*2]);   gadd[1] = hi32f(gpreB[mt*2]);
          gadd[2] = lo32f(gpreB[mt*2+1]); gadd[3] = hi32f(gpreB[mt*2+1]);
        }
        float zf[4] = { lo32f(zpreB[mt*2]),   hi32f(zpreB[mt*2]),
                        lo32f(zpreB[mt*2+1]), hi32f(zpreB[mt*2+1]) };
        f32x4 h4 = hpre4[mt];
        f32x4 hn4;
        #pragma unroll
        for (int r = 0; r < 4; r++){
          float gpre = (mt ? gb1[r] : gb0[r]) + gadd[r];
          float gv = tanhf(gpre);
          float hnv = zf[r]*h4[r] + (1.0f - zf[r])*gv;
          hn4[r] = hnv;
          rtA[c*33 + mt*16 + q*4 + r] = hnv;
          if (tb == 511) outp[OUT_OFF + ((size_t)(mt*16 + q*4 + r)*3 + lb)*H_ + nb + c] = hnv;
        }
        *(f32x4*)(hrow + ((size_t)lb*1024 + nb + c)*32 + mt*16 + q*4) = hn4;
      }
    }
    __syncthreads();
    if (actB && tid < 128){
      int b = tid & 31, p2 = tid >> 5;
      u64 pkv = pk4(rtA[(4*p2+0)*33+b], rtA[(4*p2+1)*33+b], rtA[(4*p2+2)*33+b], rtA[(4*p2+3)*33+b]);
      st64(hh + (size_t)(HIST ? (T + 1) : 0)*24576 + (size_t)lb*8192 + (size_t)((nb >> 2) + p2)*32 + b, pkv);
      if (lb == 2) *(u64*)(h2u + ((size_t)tb*32 + b)*256 + (nb >> 2) + p2) = pkv;
    }
    if constexpr (DF){
      __syncthreads();
      if (tid == 0 && actB) st_sys(flagB + i, (unsigned)(T + 2));  // slot T+1 ready
    } else {
      gbar(flags, ep); ep++;
    }
  }
  (void)ep;
}

extern "C" void kernel_launch(void* const* d_in, const int* in_sizes, int n_in,
                              void* d_out, int out_size, void* d_ws, size_t ws_size,
                              hipStream_t stream){
  (void)in_sizes; (void)n_in; (void)out_size;
  if (ws_size < WS_BASE) return;
  const bool hist = (ws_size >= WS_HIST);

  const float* x    = (const float*)d_in[0];
  const float* h0   = (const float*)d_in[1];
  const float* Wx0  = (const float*)d_in[2];
  const float* Wh0  = (const float*)d_in[3];
  const float* bh0  = (const float*)d_in[4];
  const float* Wx   = (const float*)d_in[5];
  const float* Wh   = (const float*)d_in[6];
  const float* bh   = (const float*)d_in[7];
  const float* Wout = (const float*)d_in[8];
  const float* bout = (const float*)d_in[9];
  float* out = (float*)d_out;

  char* ws = (char*)d_ws;
  unsigned short* xp    = (unsigned short*)(ws + XP_OFF);
  unsigned short* h2    = (unsigned short*)(ws + H2_OFF);
  unsigned short* xbf   = (unsigned short*)(ws + XBF_OFF);
  unsigned short* wx0b  = (unsigned short*)(ws + WX0B_OFF);
  unsigned short* wzr0  = (unsigned short*)(ws + WZR0_OFF);
  unsigned short* wg0   = (unsigned short*)(ws + WG0_OFF);
  unsigned short* wzr1  = (unsigned short*)(ws + WZR1_OFF);
  unsigned short* wgx1  = (unsigned short*)(ws + WGX1_OFF);
  unsigned short* wg1   = (unsigned short*)(ws + WG1_OFF);
  unsigned short* wzr2  = (unsigned short*)(ws + WZR2_OFF);
  unsigned short* wgx2  = (unsigned short*)(ws + WGX2_OFF);
  unsigned short* wg2   = (unsigned short*)(ws + WG2_OFF);
  unsigned short* woutb = (unsigned short*)(ws + WOUTB_OFF);
  u64* hh  = (u64*)(ws + HH_OFF);
  u64* rhh = hist ? (u64*)(ws + RHH_OFF) : (hh + 24576);

  hipMemsetAsync(ws + FLAG_OFF, 0, 4096, stream);

  k_conv<<<3072, 256, 0, stream>>>(Wx0, wx0b, 786432);
  k_conv<<<8192, 256, 0, stream>>>(Wh0, wzr0, 2097152);
  k_conv<<<4096, 256, 0, stream>>>(Wh0 + 2097152, wg0, 1048576);
  k_packzr<<<16384, 256, 0, stream>>>(Wh, Wx, wzr1);
  k_conv<<<4096, 256, 0, stream>>>(Wx + 2097152, wgx1, 1048576);
  k_conv<<<4096, 256, 0, stream>>>(Wh + 2097152, wg1, 1048576);
  k_packzr<<<16384, 256, 0, stream>>>(Wh + 3145728, Wx + 3145728, wzr2);
  k_conv<<<4096, 256, 0, stream>>>(Wx + 5242880, wgx2, 1048576);
  k_conv<<<4096, 256, 0, stream>>>(Wh + 5242880, wg2, 1048576);
  k_conv<<<1024, 256, 0, stream>>>(Wout, woutb, 262144);
  k_convx<<<16384, 256, 0, stream>>>(x, xbf);

  {
    dim3 g(24, 128);
    k_gemm<<<g, 256, 0, stream>>>(xbf, wx0b, bh0, (void*)xp, 256, 0, H3);
  }
  if (hist) k_fused<2><<<256, 256, 0, stream>>>(ws, h0, bh, out, hh, rhh);
  else      k_fused<0><<<256, 256, 0, stream>>>(ws, h0, bh, out, hh, rhh);
  {
    dim3 g(2, 128);
    k_gemm<<<g, 256, 0, stream>>>(h2, woutb, bout, (void*)out, 1024, 1, 256);
  }
}

// Round 3
// 7164.090 us; speedup vs baseline: 1.2887x; 1.0349x over previous
//
#include <hip/hip_runtime.h>
#include <cstdint>
#include <cstddef>

#define S_  512
#define H_  1024
#define H3  3072
#define OUT_OFF 4194304  // B*S*O

typedef __attribute__((ext_vector_type(8))) short  short8;
typedef __attribute__((ext_vector_type(4))) float  f32x4;
typedef __attribute__((ext_vector_type(4))) unsigned short us4;
typedef __attribute__((ext_vector_type(4))) unsigned int   u32x4;
typedef unsigned long long u64;

#define MFMA __builtin_amdgcn_mfma_f32_16x16x32_bf16

// ---- workspace layout (bytes) ----
static const size_t XP_OFF    = 0;            // bf16 [512][3072][32]
static const size_t H2_OFF    = 100663296;    // bf16 [16384][1024]
static const size_t XBF_OFF   = 134217728;    // bf16 [16384][256]
static const size_t WX0B_OFF  = 142606336;
static const size_t WZR0_OFF  = 144179200;
static const size_t WG0_OFF   = 148373504;
static const size_t WZR1_OFF  = 150470656;
static const size_t WGX1_OFF  = 158859264;
static const size_t WG1_OFF   = 160956416;
static const size_t WZR2_OFF  = 163053568;
static const size_t WGX2_OFF  = 171442176;
static const size_t WG2_OFF   = 173539328;
static const size_t WOUTB_OFF = 175636480;
static const size_t ZBU_OFF   = 176160768;    // u64 [3][1024][16] fp32-pair z
static const size_t GXB_OFF   = 176553984;    // u64 [3][1024][16] fp32-pair gx
static const size_t HROW_OFF  = 176947200;    // f32 [3][1024][32] block-local h
static const size_t FLAG_OFF  = 177340416;    // 4096: gbar flags[256] | flagA[256] | flagB[256]
static const size_t HH_OFF    = 177344512;    // hist h: u64 [515][3][256kc][32b]
static const size_t RHH_OFF   = 278597632;    // hist rh: u64 [514][3][256][32]
static const size_t WS_HIST   = 379654144;
static const size_t WS_BASE   = 177737728;    // HH used as single-slot h+rh

__device__ inline unsigned short f2bf(float f){
  unsigned u = __builtin_bit_cast(unsigned, f);
  unsigned r = u + 0x7fffu + ((u >> 16) & 1u);
  return (unsigned short)(r >> 16);
}
__device__ inline float bf2f(unsigned short s){
  unsigned u = ((unsigned)s) << 16;
  return __builtin_bit_cast(float, u);
}
// AGENT (device) scope: all communicating blocks are on one GPU. This is the
// L3 coherence point — bypasses non-coherent per-XCD L2s but is served by the
// 256MB Infinity Cache instead of DRAM (SYSTEM scope's coherence point).
__device__ inline unsigned ld_sys(const unsigned* p){
  return __hip_atomic_load(p, __ATOMIC_RELAXED, __HIP_MEMORY_SCOPE_AGENT);
}
__device__ inline void st_sys(unsigned* p, unsigned v){
  __hip_atomic_store(p, v, __ATOMIC_RELAXED, __HIP_MEMORY_SCOPE_AGENT);
}
__device__ inline u64 ld64(const u64* p){
  return __hip_atomic_load(p, __ATOMIC_RELAXED, __HIP_MEMORY_SCOPE_AGENT);
}
__device__ inline void st64(u64* p, u64 v){
  __hip_atomic_store(p, v, __ATOMIC_RELAXED, __HIP_MEMORY_SCOPE_AGENT);
}
template<bool HIST>
__device__ inline u64 LD(const u64* p){
  if constexpr (HIST) return *p; else return ld64(p);
}
__device__ inline short8 mk8u(u64 a, u64 b){
  u32x4 u; u.x = (unsigned)a; u.y = (unsigned)(a >> 32); u.z = (unsigned)b; u.w = (unsigned)(b >> 32);
  return __builtin_bit_cast(short8, u);
}
__device__ inline u64 pk4(float a, float b, float c, float d){
  return (u64)f2bf(a) | ((u64)f2bf(b) << 16) | ((u64)f2bf(c) << 32) | ((u64)f2bf(d) << 48);
}
__device__ inline u64 pk2f(float a, float b){
  return (u64)__builtin_bit_cast(unsigned, a) | ((u64)__builtin_bit_cast(unsigned, b) << 32);
}
__device__ inline float lo32f(u64 u){ return __builtin_bit_cast(float, (unsigned)u); }
__device__ inline float hi32f(u64 u){ return __builtin_bit_cast(float, (unsigned)(u >> 32)); }

// ---------------- prep kernels ----------------
__global__ void k_conv(const float* __restrict__ src, unsigned short* __restrict__ dst, int n){
  int i = blockIdx.x*256 + threadIdx.x;
  if (i < n) dst[i] = f2bf(src[i]);
}
__global__ void k_packzr(const float* __restrict__ Wh, const float* __restrict__ Wx,
                         unsigned short* __restrict__ dst){
  size_t i = (size_t)blockIdx.x*256 + threadIdx.x;
  int k = (int)(i & 2047);
  int n = (int)(i >> 11);
  float v = (k < 1024) ? Wh[(size_t)n*1024 + k] : Wx[(size_t)n*1024 + (k - 1024)];
  dst[i] = f2bf(v);
}
__global__ void k_convx(const float* __restrict__ x, unsigned short* __restrict__ xbf){
  int row = blockIdx.x;
  int s = row >> 5, b = row & 31;
  int i = threadIdx.x;
  xbf[(size_t)row*256 + i] = f2bf(x[((size_t)b*S_ + s)*256 + i]);
}

// ---------------- bf16 MFMA GEMM (proven) ----------------
__global__ __launch_bounds__(256) void k_gemm(const unsigned short* __restrict__ A,
                                              const unsigned short* __restrict__ Bw,
                                              const float* __restrict__ bias,
                                              void* __restrict__ Cout,
                                              int Kd, int mode, int Nd){
  __shared__ __align__(16) unsigned short lA[128*40];
  __shared__ __align__(16) unsigned short lB[128*40];
  int bm = blockIdx.y * 128, bn = blockIdx.x * 128;
  int tid = threadIdx.x;
  int w = tid >> 6, lane = tid & 63, q = lane >> 4, cc = lane & 15;
  int wm = (w >> 1) * 64, wn = (w & 1) * 64;
  f32x4 acc[4][4] = {};
  for (int k0 = 0; k0 < Kd; k0 += 32){
    #pragma unroll
    for (int i = 0; i < 2; i++){
      int idx = tid + i*256;
      int r = idx >> 2, ch = idx & 3;
      int m = bm + r;
      int arow = (mode == 0) ? m : ((m & 511)*32 + (m >> 9));
      *(u32x4*)(lA + r*40 + ch*8) = *(const u32x4*)(A + (size_t)arow*Kd + k0 + ch*8);
      *(u32x4*)(lB + r*40 + ch*8) = *(const u32x4*)(Bw + (size_t)(bn + r)*Kd + k0 + ch*8);
    }
    __syncthreads();
    short8 af[4], bfv[4];
    #pragma unroll
    for (int i = 0; i < 4; i++) af[i]  = *(const short8*)(lA + (wm + i*16 + cc)*40 + q*8);
    #pragma unroll
    for (int i = 0; i < 4; i++) bfv[i] = *(const short8*)(lB + (wn + i*16 + cc)*40 + q*8);
    #pragma unroll
    for (int i = 0; i < 4; i++)
      #pragma unroll
      for (int j = 0; j < 4; j++)
        acc[i][j] = MFMA(af[i], bfv[j], acc[i][j], 0, 0, 0);
    __syncthreads();
  }
  if (mode == 0){
    unsigned short* xp = (unsigned short*)Cout;
    #pragma unroll
    for (int i = 0; i < 4; i++){
      #pragma unroll
      for (int j = 0; j < 4; j++){
        int m = bm + wm + i*16 + q*4;
        int n = bn + wn + j*16 + cc;
        float bv = bias[n];
        int s = m >> 5, b0 = m & 31;
        us4 pk;
        #pragma unroll
        for (int reg = 0; reg < 4; reg++) pk[reg] = f2bf(acc[i][j][reg] + bv);
        *(us4*)(xp + ((size_t)s*H3 + n)*32 + b0) = pk;
      }
    }
  } else {
    float* C = (float*)Cout;
    #pragma unroll
    for (int i = 0; i < 4; i++){
      #pragma unroll
      for (int j = 0; j < 4; j++){
        int m = bm + wm + i*16 + q*4;
        int n = bn + wn + j*16 + cc;
        float bv = bias[n];
        #pragma unroll
        for (int reg = 0; reg < 4; reg++)
          C[(size_t)(m + reg)*Nd + n] = acc[i][j][reg] + bv;
      }
    }
  }
}

// ---------------- barriers / dataflow flags ----------------
__device__ inline void gbar(unsigned* flags, unsigned ep){
  __syncthreads();
  if (threadIdx.x == 0) st_sys(flags + blockIdx.x, ep);
  if (threadIdx.x < 64){
    for (;;){
      unsigned v0 = ld_sys(flags + threadIdx.x);
      unsigned v1 = ld_sys(flags + 64 + threadIdx.x);
      unsigned v2 = ld_sys(flags + 128 + threadIdx.x);
      unsigned v3 = ld_sys(flags + 192 + threadIdx.x);
      if (__all((v0 >= ep) && (v1 >= ep) && (v2 >= ep) && (v3 >= ep))) break;
      __builtin_amdgcn_s_sleep(1);
    }
  }
  __syncthreads();
}

// wait until flags[lo..hi) >= ep (hi-lo multiple of 64). One wave polls with
// INDEPENDENT loads (one L3 round-trip per poll), all waves released by the
// trailing block barrier.
__device__ inline void waitflags(const unsigned* f, int lo, int hi, unsigned ep){
  if (threadIdx.x < 64){
    const unsigned* p = f + lo + threadIdx.x;
    const int n = hi - lo;
    const bool h1 = (n > 64), h2 = (n > 128);
    for (;;){
      unsigned v0 = ld_sys(p);
      unsigned v1 = h1 ? ld_sys(p + 64)  : 0xffffffffu;
      unsigned v2 = h2 ? ld_sys(p + 128) : 0xffffffffu;
      if (__all((v0 >= ep) && (v1 >= ep) && (v2 >= ep))) break;
      __builtin_amdgcn_s_sleep(1);
    }
  }
  __syncthreads();
}

// matvec, k-major A layout [kc][b] (u64 chunks of 4 bf16).
// p0 = base + (kc0 + q*2)*32 + c ; per iter +256 (8 chunks). acc1 = b+16.
template<int NITER, bool HIST>
__device__ inline void matvec(const u64* p0, const unsigned short* wp,
                              f32x4& acc0, f32x4& acc1){
  u64 buf[2][4][4];
  #pragma unroll
  for (int ii = 0; ii < 4; ii++){
    const u64* p = p0 + ii*256;
    buf[0][ii][0] = LD<HIST>(p);      buf[0][ii][1] = LD<HIST>(p + 32);
    buf[0][ii][2] = LD<HIST>(p + 16); buf[0][ii][3] = LD<HIST>(p + 48);
  }
  constexpr int NCH = NITER / 4;
  #pragma unroll
  for (int ch = 0; ch < NCH; ch++){
    const int cur = ch & 1, nxt = cur ^ 1;
    if (ch + 1 < NCH){
      #pragma unroll
      for (int ii = 0; ii < 4; ii++){
        const u64* p = p0 + ((ch+1)*4 + ii)*256;
        buf[nxt][ii][0] = LD<HIST>(p);      buf[nxt][ii][1] = LD<HIST>(p + 32);
        buf[nxt][ii][2] = LD<HIST>(p + 16); buf[nxt][ii][3] = LD<HIST>(p + 48);
      }
    }
    #pragma unroll
    for (int ii = 0; ii < 4; ii++){
      short8 bw = *(const short8*)(wp + (ch*4 + ii)*32);
      acc0 = MFMA(mk8u(buf[cur][ii][0], buf[cur][ii][1]), bw, acc0, 0, 0, 0);
      acc1 = MFMA(mk8u(buf[cur][ii][2], buf[cur][ii][3]), bw, acc1, 0, 0, 0);
    }
  }
}

// ---------------- fused 3-layer pipelined persistent recurrence ----------------
// MODE 0: single-slot, global barriers.  MODE 2: per-T slots, point-to-point
// dataflow flags (no grid-wide barrier).
template<int MODE>
__global__ __launch_bounds__(256, 1) void k_fused(char* __restrict__ ws,
                                                  const float* __restrict__ h0,
                                                  const float* __restrict__ bh,
                                                  float* __restrict__ outp,
                                                  u64* __restrict__ hh,
                                                  u64* __restrict__ rhh){
  constexpr bool HIST = (MODE >= 1);
  constexpr bool DF   = (MODE == 2);

  __shared__ __align__(16) unsigned short wlds[65920];
  __shared__ __align__(16) float red[2][3][64][10];
  __shared__ float rtA[16*33];
  __shared__ float rtB[16*33];

  const int tid = threadIdx.x;
  const int w = tid >> 6, lane = tid & 63, q = (lane >> 4) & 3, c = lane & 15;
  const int i = blockIdx.x;

  const int lz   = 1 + (i >> 7);
  const int g2   = (i >> 6) & 1;
  const int n2   = (i & 63) << 4;
  const bool isl0 = (i < 128);
  const int g1   = (i >> 6) & 1;
  const int lgx  = 1 + ((i >> 6) & 1);
  const int n1   = (i & 63) << 4;
  const bool hasB = (i < 192);
  const int lb   = i >> 6;
  const int nb   = (i & 63) << 4;

  // phase-B consumers wait on phase-A producers in these block ranges
  const int alo = (lb == 2) ? 128 : 0;
  const int ahi = (lb == 0) ? 128 : (lb == 1 ? 192 : 256);

  const unsigned short* xp = (const unsigned short*)(ws + XP_OFF);
  u64* h2u   = (u64*)(ws + H2_OFF);
  u64* zbu   = (u64*)(ws + ZBU_OFF);
  u64* gxb   = (u64*)(ws + GXB_OFF);
  float* hrow = (float*)(ws + HROW_OFF);
  unsigned* flags = (unsigned*)(ws + FLAG_OFF);
  unsigned* flagA = flags + 256;   // per-block phase-A completion epoch
  unsigned* flagB = flags + 512;   // per-block phase-B completion epoch

  // ---- stage weights into LDS ----
  {
    const unsigned short* src2 = (const unsigned short*)(ws + (lz == 1 ? WZR1_OFF : WZR2_OFF))
                                 + (size_t)(g2*1024 + n2)*2048;
    for (int idx = tid; idx < 4096; idx += 256){
      int kc = idx & 255, row = idx >> 8;
      u32x4 v = *(const u32x4*)(src2 + (size_t)row*2048 + kc*8);
      *(u32x4*)(wlds + row*2056 + kc*8) = v;
    }
    const unsigned short* src1 = isl0
      ? (const unsigned short*)(ws + WZR0_OFF) + (size_t)(g1*1024 + n1)*1024
      : (const unsigned short*)(ws + (lgx == 1 ? WGX1_OFF : WGX2_OFF)) + (size_t)n1*1024;
    for (int idx = tid; idx < 2048; idx += 256){
      int kc = idx & 127, row = idx >> 7;
      u32x4 v = *(const u32x4*)(src1 + (size_t)row*1024 + kc*8);
      *(u32x4*)(wlds + 32896 + row*1032 + kc*8) = v;
    }
    if (hasB){
      const unsigned short* srcb = (const unsigned short*)(ws + (lb == 0 ? WG0_OFF : (lb == 1 ? WG1_OFF : WG2_OFF)))
                                   + (size_t)nb*1024;
      for (int idx = tid; idx < 2048; idx += 256){
        int kc = idx & 127, row = idx >> 7;
        u32x4 v = *(const u32x4*)(srcb + (size_t)row*1024 + kc*8);
        *(u32x4*)(wlds + 49408 + row*1032 + kc*8) = v;
      }
    }
  }
  const float biasT2 = bh[(size_t)(lz-1)*H3 + g2*1024 + n2 + c];
  const float biasGX = isl0 ? 0.f : bh[(size_t)(lgx-1)*H3 + 2048 + n1 + c];

  // ---- init h state ----
  if (hasB){
    for (int idx = tid; idx < 512; idx += 256){
      int n = idx >> 5, b = idx & 31;
      float v = h0[((size_t)b*3 + lb)*H_ + nb + n];
      hrow[((size_t)lb*1024 + nb + n)*32 + b] = v;
      rtA[n*33 + b] = v;
    }
  }
  __syncthreads();
  if (hasB && tid < 128){
    int b = tid & 31, p2 = tid >> 5;
    u64 pkv = pk4(rtA[(4*p2+0)*33+b], rtA[(4*p2+1)*33+b], rtA[(4*p2+2)*33+b], rtA[(4*p2+3)*33+b]);
    st64(hh + (size_t)(HIST ? lb : 0)*24576 + (size_t)lb*8192 + (size_t)((nb >> 2) + p2)*32 + b, pkv);
  }
  unsigned ep = 1;
  if constexpr (DF){
    __syncthreads();
    if (tid == 0 && hasB) st_sys(flagB + i, (unsigned)(lb + 1));  // slot lb ready
  } else {
    gbar(flags, ep); ep++;
  }

  for (int T = 0; T < 514; T++){
    const int t2 = T - lz;
    const bool actT2 = (unsigned)t2 < 512u;
    const int t1 = isl0 ? T : (T - lgx);
    const bool actT1 = (unsigned)t1 < 512u;
    const int tb = T - lb;
    const bool actB = hasB && ((unsigned)tb < 512u);

    const u64* hslotR = hh + (size_t)(HIST ? T : 0)*24576;
    u64*       rslot  = rhh + (size_t)(HIST ? T : 0)*24576;

    if constexpr (DF){
      // wait for hh slot T (layers this block reads) + WAR cover for zbu/gxb
      int lo = 256, hi = 0;
      if (actT2){ int a = 64*(lz-1), b = 64*(lz+1); if (a < lo) lo = a; if (b > hi) hi = b; }
      if (actT1){
        int a = isl0 ? 0 : 64*(lgx-1);
        int b = isl0 ? 64 : 64*(lgx+1);
        if (a < lo) lo = a; if (b > hi) hi = b;
      }
      if (hi > lo) waitflags(flagB, lo, hi, (unsigned)(T + 1));
    }

    // ---- prefetch phase-A epilogue operands (hide L3 latency under matvec) ----
    u64 hpreA[8]; us4 xpreA[2]; u64 hpreL0[8];
    if (actT2 && w == 0 && g2 == 1){
      const u64* hb = hslotR + (size_t)lz*8192 + (size_t)((n2 + c) >> 2)*32 + q*4;
      #pragma unroll
      for (int mt = 0; mt < 2; mt++)
        #pragma unroll
        for (int r = 0; r < 4; r++) hpreA[mt*4+r] = LD<HIST>(hb + mt*16 + r);
    }
    if (actT1 && w == 1 && isl0){
      const unsigned short* xr = xp + ((size_t)t1*H3 + g1*1024 + n1 + c)*32 + q*4;
      xpreA[0] = *(const us4*)(xr);
      xpreA[1] = *(const us4*)(xr + 16);
      if (g1 == 1){
        const u64* hb = hslotR + (size_t)((n1 + c) >> 2)*32 + q*4;
        #pragma unroll
        for (int mt = 0; mt < 2; mt++)
          #pragma unroll
          for (int r = 0; r < 4; r++) hpreL0[mt*4+r] = LD<HIST>(hb + mt*16 + r);
      }
    }

    // ================= phase A =================
    f32x4 z20 = {0,0,0,0}, z21 = {0,0,0,0};
    f32x4 z10 = {0,0,0,0}, z11 = {0,0,0,0};
    if (actT2){
      const u64* p0 = hslotR + (size_t)((w < 2) ? lz : (lz-1))*8192 + (size_t)((w & 1)*128 + q*2)*32 + c;
      const unsigned short* wp = wlds + c*2056 + w*512 + q*8;
      matvec<16, HIST>(p0, wp, z20, z21);
    }
    if (actT1){
      const u64* p0 = hslotR + (size_t)(isl0 ? 0 : (lgx-1))*8192 + (size_t)(w*64 + q*2)*32 + c;
      const unsigned short* wp = wlds + 32896 + c*1032 + w*256 + q*8;
      matvec<8, HIST>(p0, wp, z10, z11);
    }
    if (actT2 && w > 0){
      float* p = &red[0][w-1][lane][0];
      #pragma unroll
      for (int r = 0; r < 4; r++){ p[r] = z20[r]; p[4+r] = z21[r]; }
    }
    if (actT1 && w != 1){
      float* p = &red[1][(w == 0) ? 0 : (w-1)][lane][0];
      #pragma unroll
      for (int r = 0; r < 4; r++){ p[r] = z10[r]; p[4+r] = z11[r]; }
    }
    __syncthreads();
    if (w == 0 && actT2){
      #pragma unroll
      for (int s = 0; s < 3; s++){
        const float* p = &red[0][s][lane][0];
        #pragma unroll
        for (int r = 0; r < 4; r++){ z20[r] += p[r]; z21[r] += p[4+r]; }
      }
      const int sh = (c & 3)*16;
      #pragma unroll
      for (int mt = 0; mt < 2; mt++){
        float f[4];
        #pragma unroll
        for (int r = 0; r < 4; r++){
          float pre = (mt ? z21[r] : z20[r]) + biasT2;
          f[r] = 1.0f / (1.0f + __expf(-pre));
        }
        if (g2 == 0){
          u64* zp = zbu + ((size_t)lz*1024 + n2 + c)*16 + mt*8 + q*2;
          st64(zp, pk2f(f[0], f[1])); st64(zp + 1, pk2f(f[2], f[3]));
        } else {
          #pragma unroll
          for (int r = 0; r < 4; r++){
            int b = mt*16 + q*4 + r;
            rtA[c*33 + b] = f[r] * bf2f((unsigned short)(hpreA[mt*4+r] >> sh));
          }
        }
      }
    }
    if (w == 1 && actT1){
      #pragma unroll
      for (int s = 0; s < 3; s++){
        const float* p = &red[1][s][lane][0];
        #pragma unroll
        for (int r = 0; r < 4; r++){ z10[r] += p[r]; z11[r] += p[4+r]; }
      }
      if (isl0){
        const int sh = (c & 3)*16;
        #pragma unroll
        for (int mt = 0; mt < 2; mt++){
          us4 xv = xpreA[mt];
          float f[4];
          #pragma unroll
          for (int r = 0; r < 4; r++){
            float pre = (mt ? z11[r] : z10[r]) + bf2f(xv[r]);
            f[r] = 1.0f / (1.0f + __expf(-pre));
          }
          if (g1 == 0){
            u64* zp = zbu + ((size_t)n1 + c)*16 + mt*8 + q*2;
            st64(zp, pk2f(f[0], f[1])); st64(zp + 1, pk2f(f[2], f[3]));
          } else {
            #pragma unroll
            for (int r = 0; r < 4; r++){
              int b = mt*16 + q*4 + r;
              rtB[c*33 + b] = f[r] * bf2f((unsigned short)(hpreL0[mt*4+r] >> sh));
            }
          }
        }
      } else {
        #pragma unroll
        for (int mt = 0; mt < 2; mt++){
          float f[4];
          #pragma unroll
          for (int r = 0; r < 4; r++) f[r] = (mt ? z11[r] : z10[r]) + biasGX;
          u64* gp = gxb + ((size_t)lgx*1024 + n1 + c)*16 + mt*8 + q*2;
          st64(gp, pk2f(f[0], f[1])); st64(gp + 1, pk2f(f[2], f[3]));
        }
      }
    }
    __syncthreads();
    if (g2 == 1 && actT2 && tid < 128){
      int b = tid & 31, p2 = tid >> 5;
      st64(rslot + (size_t)lz*8192 + (size_t)((n2 >> 2) + p2)*32 + b,
           pk4(rtA[(4*p2+0)*33+b], rtA[(4*p2+1)*33+b], rtA[(4*p2+2)*33+b], rtA[(4*p2+3)*33+b]));
    }
    if (isl0 && g1 == 1 && actT1 && tid >= 128){
      int tt = tid - 128; int b = tt & 31, p2 = tt >> 5;
      st64(rslot + (size_t)((n1 >> 2) + p2)*32 + b,
           pk4(rtB[(4*p2+0)*33+b], rtB[(4*p2+1)*33+b], rtB[(4*p2+2)*33+b], rtB[(4*p2+3)*33+b]));
    }
    if constexpr (DF){
      __syncthreads();
      if (tid == 0 && (actT2 || actT1)) st_sys(flagA + i, (unsigned)(T + 1));
      if (actB) waitflags(flagA, alo, ahi, (unsigned)(T + 1));
    } else {
      gbar(flags, ep); ep++;
    }

    // ---- prefetch phase-B epilogue operands (hide L3 latency under matvec) ----
    u64 zpreB[4], gpreB[4]; us4 xpreB[2]; f32x4 hpre4[2];
    if (actB && w == 0){
      const u64* zp = zbu + ((size_t)lb*1024 + nb + c)*16 + q*2;
      zpreB[0] = ld64(zp);     zpreB[1] = ld64(zp + 1);
      zpreB[2] = ld64(zp + 8); zpreB[3] = ld64(zp + 9);
      if (lb == 0){
        const unsigned short* xr = xp + ((size_t)tb*H3 + 2048 + nb + c)*32 + q*4;
        xpreB[0] = *(const us4*)(xr);
        xpreB[1] = *(const us4*)(xr + 16);
      } else {
        const u64* gp = gxb + ((size_t)lb*1024 + nb + c)*16 + q*2;
        gpreB[0] = ld64(gp);     gpreB[1] = ld64(gp + 1);
        gpreB[2] = ld64(gp + 8); gpreB[3] = ld64(gp + 9);
      }
      const float* hp0 = hrow + ((size_t)lb*1024 + nb + c)*32 + q*4;
      hpre4[0] = *(const f32x4*)(hp0);
      hpre4[1] = *(const f32x4*)(hp0 + 16);
    }

    // ================= phase B =================
    f32x4 gb0 = {0,0,0,0}, gb1 = {0,0,0,0};
    if (actB){
      const u64* p0 = (const u64*)rslot + (size_t)lb*8192 + (size_t)(w*64 + q*2)*32 + c;
      const unsigned short* wp = wlds + 49408 + c*1032 + w*256 + q*8;
      matvec<8, HIST>(p0, wp, gb0, gb1);
      if (w > 0){
        float* p = &red[0][w-1][lane][0];
        #pragma unroll
        for (int r = 0; r < 4; r++){ p[r] = gb0[r]; p[4+r] = gb1[r]; }
      }
    }
    __syncthreads();
    if (actB && w == 0){
      #pragma unroll
      for (int s = 0; s < 3; s++){
        const float* p = &red[0][s][lane][0];
        #pragma unroll
        for (int r = 0; r < 4; r++){ gb0[r] += p[r]; gb1[r] += p[4+r]; }
      }
      #pragma unroll
      for (int mt = 0; mt < 2; mt++){
        float gadd[4];
        if (lb == 0){
          us4 xv = xpreB[mt];
          #pragma unroll
          for (int r = 0; r < 4; r++) gadd[r] = bf2f(xv[r]);
        } else {
          gadd[0] = lo32f(gpreB[mt*2]);   gadd[1] = hi32f(gpreB[mt*2]);
          gadd[2] = lo32f(gpreB[mt*2+1]); gadd[3] = hi32f(gpreB[mt*2+1]);
        }
        float zf[4] = { lo32f(zpreB[mt*2]),   hi32f(zpreB[mt*2]),
                        lo32f(zpreB[mt*2+1]), hi32f(zpreB[mt*2+1]) };
        f32x4 h4 = hpre4[mt];
        f32x4 hn4;
        #pragma unroll
        for (int r = 0; r < 4; r++){
          float gpre = (mt ? gb1[r] : gb0[r]) + gadd[r];
          float gv = tanhf(gpre);
          float hnv = zf[r]*h4[r] + (1.0f - zf[r])*gv;
          hn4[r] = hnv;
          rtA[c*33 + mt*16 + q*4 + r] = hnv;
          if (tb == 511) outp[OUT_OFF + ((size_t)(mt*16 + q*4 + r)*3 + lb)*H_ + nb + c] = hnv;
        }
        *(f32x4*)(hrow + ((size_t)lb*1024 + nb + c)*32 + mt*16 + q*4) = hn4;
      }
    }
    __syncthreads();
    if (actB && tid < 128){
      int b = tid & 31, p2 = tid >> 5;
      u64 pkv = pk4(rtA[(4*p2+0)*33+b], rtA[(4*p2+1)*33+b], rtA[(4*p2+2)*33+b], rtA[(4*p2+3)*33+b]);
      st64(hh + (size_t)(HIST ? (T + 1) : 0)*24576 + (size_t)lb*8192 + (size_t)((nb >> 2) + p2)*32 + b, pkv);
      if (lb == 2) *(u64*)(h2u + ((size_t)tb*32 + b)*256 + (nb >> 2) + p2) = pkv;
    }
    if constexpr (DF){
      __syncthreads();
      if (tid == 0 && actB) st_sys(flagB + i, (unsigned)(T + 2));  // slot T+1 ready
    } else {
      gbar(flags, ep); ep++;
    }
  }
  (void)ep;
}

extern "C" void kernel_launch(void* const* d_in, const int* in_sizes, int n_in,
                              void* d_out, int out_size, void* d_ws, size_t ws_size,
                              hipStream_t stream){
  (void)in_sizes; (void)n_in; (void)out_size;
  if (ws_size < WS_BASE) return;
  const bool hist = (ws_size >= WS_HIST);

  const float* x    = (const float*)d_in[0];
  const float* h0   = (const float*)d_in[1];
  const float* Wx0  = (const float*)d_in[2];
  const float* Wh0  = (const float*)d_in[3];
  const float* bh0  = (const float*)d_in[4];
  const float* Wx   = (const float*)d_in[5];
  const float* Wh   = (const float*)d_in[6];
  const float* bh   = (const float*)d_in[7];
  const float* Wout = (const float*)d_in[8];
  const float* bout = (const float*)d_in[9];
  float* out = (float*)d_out;

  char* ws = (char*)d_ws;
  unsigned short* xp    = (unsigned short*)(ws + XP_OFF);
  unsigned short* h2    = (unsigned short*)(ws + H2_OFF);
  unsigned short* xbf   = (unsigned short*)(ws + XBF_OFF);
  unsigned short* wx0b  = (unsigned short*)(ws + WX0B_OFF);
  unsigned short* wzr0  = (unsigned short*)(ws + WZR0_OFF);
  unsigned short* wg0   = (unsigned short*)(ws + WG0_OFF);
  unsigned short* wzr1  = (unsigned short*)(ws + WZR1_OFF);
  unsigned short* wgx1  = (unsigned short*)(ws + WGX1_OFF);
  unsigned short* wg1   = (unsigned short*)(ws + WG1_OFF);
  unsigned short* wzr2  = (unsigned short*)(ws + WZR2_OFF);
  unsigned short* wgx2  = (unsigned short*)(ws + WGX2_OFF);
  unsigned short* wg2   = (unsigned short*)(ws + WG2_OFF);
  unsigned short* woutb = (unsigned short*)(ws + WOUTB_OFF);
  u64* hh  = (u64*)(ws + HH_OFF);
  u64* rhh = hist ? (u64*)(ws + RHH_OFF) : (hh + 24576);

  hipMemsetAsync(ws + FLAG_OFF, 0, 4096, stream);

  k_conv<<<3072, 256, 0, stream>>>(Wx0, wx0b, 786432);
  k_conv<<<8192, 256, 0, stream>>>(Wh0, wzr0, 2097152);
  k_conv<<<4096, 256, 0, stream>>>(Wh0 + 2097152, wg0, 1048576);
  k_packzr<<<16384, 256, 0, stream>>>(Wh, Wx, wzr1);
  k_conv<<<4096, 256, 0, stream>>>(Wx + 2097152, wgx1, 1048576);
  k_conv<<<4096, 256, 0, stream>>>(Wh + 2097152, wg1, 1048576);
  k_packzr<<<16384, 256, 0, stream>>>(Wh + 3145728, Wx + 3145728, wzr2);
  k_conv<<<4096, 256, 0, stream>>>(Wx + 5242880, wgx2, 1048576);
  k_conv<<<4096, 256, 0, stream>>>(Wh + 5242880, wg2, 1048576);
  k_conv<<<1024, 256, 0, stream>>>(Wout, woutb, 262144);
  k_convx<<<16384, 256, 0, stream>>>(x, xbf);

  {
    dim3 g(24, 128);
    k_gemm<<<g, 256, 0, stream>>>(xbf, wx0b, bh0, (void*)xp, 256, 0, H3);
  }
  if (hist) k_fused<2><<<256, 256, 0, stream>>>(ws, h0, bh, out, hh, rhh);
  else      k_fused<0><<<256, 256, 0, stream>>>(ws, h0, bh, out, hh, rhh);
  {
    dim3 g(2, 128);
    k_gemm<<<g, 256, 0, stream>>>(h2, woutb, bout, (void*)out, 1024, 1, 256);
  }
}